// Round 4
// baseline (689.647 us; speedup 1.0000x reference)
//
#include <hip/hip_runtime.h>

#define T_N 1024
#define H_N 128
#define CH   64
#define NCH (T_N / CH)   // 16
#define WPAD 136         // short stride for [n][k] weight tiles (16B-aligned rows, conflict-light)
#define PPAD 68          // float stride for pbuf_T rows (16B-aligned, conflict-free reads)

typedef __attribute__((ext_vector_type(8))) short bf16x8;
typedef __attribute__((ext_vector_type(4))) float f32x4;

__device__ __forceinline__ short f2bf_rne(float f) {
    union { float f; unsigned int i; } v; v.f = f;
    unsigned int r = v.i + 0x7FFFu + ((v.i >> 16) & 1u);
    return (short)(r >> 16);
}
__device__ __forceinline__ float tanh_fast(float x) {
    return 1.0f - 2.0f / (__expf(2.0f * x) + 1.0f);
}

// One block = one wave = one batch row. MFMA matvec recurrence, barrier-free.
__global__ __launch_bounds__(64, 1) void k_fused(const float* __restrict__ x,
                                                 const float* __restrict__ w,
                                                 const float* __restrict__ wst,
                                                 const float* __restrict__ bias,
                                                 float* __restrict__ out) {
    __shared__ __align__(16) short wT[H_N * WPAD];    // input-proj w, bf16 [n][k]
    __shared__ __align__(16) short wsT[H_N * WPAD];   // state w,     bf16 [n][k]
    __shared__ __align__(16) float pT[H_N * PPAD];    // proj chunk, [h][t_local]
    __shared__ __align__(16) short sst[H_N];          // state, bf16

    const int lane = threadIdx.x;       // 0..63
    const int l = lane & 15;
    const int q = lane >> 4;
    const int r = blockIdx.x;           // batch row
    const float* xrow = x + (size_t)r * T_N * H_N;

    // ---- stage x for chunk 0 (issue first: hide HBM latency under LDS init) ----
    float4 xs[4][4][2];   // [rt][ks][half] : x[c*64+rt*16+l][32ks+8q .. +7]
    #pragma unroll
    for (int rt = 0; rt < 4; ++rt)
        #pragma unroll
        for (int ks = 0; ks < 4; ++ks) {
            const float* p = xrow + (size_t)(rt * 16 + l) * H_N + ks * 32 + q * 8;
            xs[rt][ks][0] = *reinterpret_cast<const float4*>(p);
            xs[rt][ks][1] = *reinterpret_cast<const float4*>(p + 4);
        }

    // ---- one-time: fp32 weights -> bf16 [n][k] LDS tiles ----
    for (int e0 = lane * 4; e0 < H_N * H_N; e0 += 256) {
        int k = e0 >> 7, n = e0 & 127;
        float4 a = *reinterpret_cast<const float4*>(w + e0);
        wT[(n + 0) * WPAD + k] = f2bf_rne(a.x);
        wT[(n + 1) * WPAD + k] = f2bf_rne(a.y);
        wT[(n + 2) * WPAD + k] = f2bf_rne(a.z);
        wT[(n + 3) * WPAD + k] = f2bf_rne(a.w);
        float4 b = *reinterpret_cast<const float4*>(wst + e0);
        wsT[(n + 0) * WPAD + k] = f2bf_rne(b.x);
        wsT[(n + 1) * WPAD + k] = f2bf_rne(b.y);
        wsT[(n + 2) * WPAD + k] = f2bf_rne(b.z);
        wsT[(n + 3) * WPAD + k] = f2bf_rne(b.w);
    }

    // ---- persistent registers: state-W B-frags + bias ----
    bf16x8 wf[8][4];   // wf[nt][ks]: lane holds wst[32ks+8q+j][16nt+l]
    #pragma unroll
    for (int nt = 0; nt < 8; ++nt)
        #pragma unroll
        for (int ks = 0; ks < 4; ++ks)
            wf[nt][ks] = *reinterpret_cast<const bf16x8*>(
                &wsT[(nt * 16 + l) * WPAD + ks * 32 + q * 8]);

    float bv[8];
    #pragma unroll
    for (int nt = 0; nt < 8; ++nt) bv[nt] = bias[nt * 16 + l];

    const bool isq0 = (q == 0), isq1 = (q == 1), isq2 = (q == 2);
    float y0 = 0.f, y1 = 0.f;

    #pragma unroll 1
    for (int c = 0; c < NCH; ++c) {
        // ---- cvt staged x -> A-frags (releases xs for next chunk's loads) ----
        bf16x8 ax[4][4];
        #pragma unroll
        for (int rt = 0; rt < 4; ++rt)
            #pragma unroll
            for (int ks = 0; ks < 4; ++ks) {
                bf16x8 f;
                #pragma unroll
                for (int j = 0; j < 4; ++j) {
                    f[j]     = f2bf_rne(((const float*)&xs[rt][ks][0])[j]);
                    f[j + 4] = f2bf_rne(((const float*)&xs[rt][ks][1])[j]);
                }
                ax[rt][ks] = f;
            }

        // ---- issue x staging loads for chunk c+1 (complete during recurrence) ----
        if (c + 1 < NCH) {
            #pragma unroll
            for (int rt = 0; rt < 4; ++rt)
                #pragma unroll
                for (int ks = 0; ks < 4; ++ks) {
                    const float* p = xrow + (size_t)((c + 1) * CH + rt * 16 + l) * H_N
                                     + ks * 32 + q * 8;
                    xs[rt][ks][0] = *reinterpret_cast<const float4*>(p);
                    xs[rt][ks][1] = *reinterpret_cast<const float4*>(p + 4);
                }
        }

        // ---- proj GEMM for this chunk: pT[h][t] = x@w + bias ----
        #pragma unroll
        for (int nt = 0; nt < 8; ++nt) {
            bf16x8 bw[4];
            #pragma unroll
            for (int ks = 0; ks < 4; ++ks)
                bw[ks] = *reinterpret_cast<const bf16x8*>(
                    &wT[(nt * 16 + l) * WPAD + ks * 32 + q * 8]);
            #pragma unroll
            for (int rt = 0; rt < 4; ++rt) {
                f32x4 acc = (f32x4){0.f, 0.f, 0.f, 0.f};
                #pragma unroll
                for (int ks = 0; ks < 4; ++ks)
                    acc = __builtin_amdgcn_mfma_f32_16x16x32_bf16(ax[rt][ks], bw[ks], acc, 0, 0, 0);
                // D: col h=16nt+l, rows t_loc = rt*16 + q*4 + i
                f32x4 o = (f32x4){acc[0] + bv[nt], acc[1] + bv[nt],
                                  acc[2] + bv[nt], acc[3] + bv[nt]};
                *reinterpret_cast<f32x4*>(&pT[(nt * 16 + l) * PPAD + rt * 16 + q * 4]) = o;
            }
        }

        int tstart = 0;
        if (c == 0) {
            // state0 = tanh(proj[0]) — no recurrent term
            float p0 = pT[(32 * q + l) * PPAD + 0];
            float p1 = pT[(32 * q + 16 + l) * PPAD + 0];
            sst[32 * q + l]      = f2bf_rne(tanh_fast(p0));
            sst[32 * q + 16 + l] = f2bf_rne(tanh_fast(p1));
            tstart = 1;
        }

        // ---- recurrence: 1 wave, no barriers ----
        #pragma unroll 1
        for (int t = tstart; t < CH; ++t) {
            // A-frags: every lane reads the same state chunk for its q -> all 16 A rows = s
            bf16x8 a[4];
            #pragma unroll
            for (int ks = 0; ks < 4; ++ks)
                a[ks] = *reinterpret_cast<const bf16x8*>(&sst[ks * 32 + q * 8]);

            f32x4 acc[8];
            #pragma unroll
            for (int nt = 0; nt < 8; ++nt) {
                float p = pT[(nt * 16 + l) * PPAD + t];  // broadcast over q
                acc[nt] = (f32x4){p, 0.f, 0.f, 0.f};     // C reg0 = row 4q: the row we read
                #pragma unroll
                for (int ks = 0; ks < 4; ++ks)
                    acc[nt] = __builtin_amdgcn_mfma_f32_16x16x32_bf16(a[ks], wf[nt][ks], acc[nt], 0, 0, 0);
            }

            // lane (q,l) finalizes cols 32q+l and 32q+16+l  (n-tiles 2q, 2q+1)
            float z0 = isq0 ? acc[0][0] : isq1 ? acc[2][0] : isq2 ? acc[4][0] : acc[6][0];
            float z1 = isq0 ? acc[1][0] : isq1 ? acc[3][0] : isq2 ? acc[5][0] : acc[7][0];
            y0 = tanh_fast(z0);
            y1 = tanh_fast(z1);
            sst[32 * q + l]      = f2bf_rne(y0);
            sst[32 * q + 16 + l] = f2bf_rne(y1);
        }
    }

    // final state, fp32 from the last step's registers
    out[r * H_N + 32 * q + l]      = y0;
    out[r * H_N + 32 * q + 16 + l] = y1;
}

extern "C" void kernel_launch(void* const* d_in, const int* in_sizes, int n_in,
                              void* d_out, int out_size, void* d_ws, size_t ws_size,
                              hipStream_t stream) {
    const float* x    = (const float*)d_in[0];  // [B][T][D] fp32
    const float* w    = (const float*)d_in[1];  // [D][H]    fp32
    const float* wst  = (const float*)d_in[2];  // [H][H]    fp32
    const float* bias = (const float*)d_in[3];  // [H]       fp32
    float* out = (float*)d_out;                 // [B][H]    fp32

    k_fused<<<256, 64, 0, stream>>>(x, w, wst, bias, out);
}

// Round 5
// 661.372 us; speedup vs baseline: 1.0428x; 1.0428x over previous
//
#include <hip/hip_runtime.h>

#define T_N 1024
#define H_N 128
#define CH   64
#define NCH (T_N / CH)     // 16
#define WPAD 136           // shorts per row of bf16 weight tiles (16B-aligned, 2-way-free reads)
#define PPAD 68            // floats per row of pT (16B-aligned, 2-way-free step reads)
#define XGRP 1040          // bytes per 2-row group in xbuf: 1024 data + 16 pad (bank spread)
#define XBUF_BYTES (32 * XGRP)   // 33280 per chunk buffer

typedef __attribute__((ext_vector_type(8))) short bf16x8;
typedef __attribute__((ext_vector_type(4))) float f32x4;

__device__ __forceinline__ short f2bf_rne(float f) {
    union { float f; unsigned int i; } v; v.f = f;
    unsigned int r = v.i + 0x7FFFu + ((v.i >> 16) & 1u);
    return (short)(r >> 16);
}
__device__ __forceinline__ float tanh_fast(float x) {
    return 1.0f - 2.0f / (__expf(2.0f * x) + 1.0f);
}

// One block = one wave = one batch row. MFMA matvec recurrence, barrier-light.
// x prefetched via global_load_lds DMA (no staging VGPRs -> no step-loop spills).
__global__ __launch_bounds__(64, 1) void k_fused(const float* __restrict__ x,
                                                 const float* __restrict__ w,
                                                 const float* __restrict__ wst,
                                                 const float* __restrict__ bias,
                                                 float* __restrict__ out) {
    __shared__ __align__(16) short wT[H_N * WPAD];     // 34816 B: input-proj w, bf16 [n][k]
    __shared__ __align__(16) float pT[H_N * PPAD];     // 34816 B: proj chunk [h][t]; wsT staging at startup
    __shared__ __align__(16) char  xbuf[2][XBUF_BYTES];// 66560 B: fp32 x chunk, DMA double buffer
    __shared__ __align__(16) short sst[H_N];           // 256 B: state, bf16

    const int lane = threadIdx.x;   // 0..63
    const int l = lane & 15;
    const int q = lane >> 4;
    const int r = blockIdx.x;
    const float* xrow = x + (size_t)r * T_N * H_N;

    const f32x4 zero4 = (f32x4){0.f, 0.f, 0.f, 0.f};

    // ---- issue DMA for chunk 0 immediately (drains at first __syncthreads) ----
    {
        const char* gsrc = (const char*)xrow;
        #pragma unroll 1
        for (int k = 0; k < 32; ++k) {
            __builtin_amdgcn_global_load_lds(
                (const __attribute__((address_space(1))) void*)(gsrc + k * 1024 + lane * 16),
                (__attribute__((address_space(3))) void*)(&xbuf[0][k * XGRP]),
                16, 0, 0);
        }
    }

    // ---- stage wst (bf16, [n][k]) through pT's memory, then lift wf into regs ----
    short* wsT = reinterpret_cast<short*>(pT);
    for (int e = lane * 4; e < H_N * H_N; e += 256) {
        int k = e >> 7, n = e & 127;                      // wst[k][n..n+3]
        float4 a4 = *reinterpret_cast<const float4*>(wst + e);
        wsT[(n + 0) * WPAD + k] = f2bf_rne(a4.x);
        wsT[(n + 1) * WPAD + k] = f2bf_rne(a4.y);
        wsT[(n + 2) * WPAD + k] = f2bf_rne(a4.z);
        wsT[(n + 3) * WPAD + k] = f2bf_rne(a4.w);
    }
    // single wave: DS ops are in-order, reads below see the writes above
    bf16x8 wf[8][4];   // wf[nt][ks]: lane holds wst[32ks+8q+j][16nt+l]  (128 VGPRs, persistent)
    #pragma unroll
    for (int nt = 0; nt < 8; ++nt)
        #pragma unroll
        for (int ks = 0; ks < 4; ++ks)
            wf[nt][ks] = *reinterpret_cast<const bf16x8*>(
                &wsT[(nt * 16 + l) * WPAD + ks * 32 + q * 8]);

    // ---- input-proj weights -> bf16 [n][k] LDS ----
    for (int e = lane * 4; e < H_N * H_N; e += 256) {
        int k = e >> 7, n = e & 127;
        float4 a4 = *reinterpret_cast<const float4*>(w + e);
        wT[(n + 0) * WPAD + k] = f2bf_rne(a4.x);
        wT[(n + 1) * WPAD + k] = f2bf_rne(a4.y);
        wT[(n + 2) * WPAD + k] = f2bf_rne(a4.z);
        wT[(n + 3) * WPAD + k] = f2bf_rne(a4.w);
    }

    float bv[8];
    #pragma unroll
    for (int nt = 0; nt < 8; ++nt) bv[nt] = bias[nt * 16 + l];

    const bool isq0 = (q == 0), isq1 = (q == 1), isq2 = (q == 2);
    float y0 = 0.f, y1 = 0.f;

    #pragma unroll 1
    for (int c = 0; c < NCH; ++c) {
        // drain DMA for this chunk's xbuf (also fences wsT-staging reads vs pT writes at c=0)
        __syncthreads();

        // ---- proj GEMM for chunk c: pT[h][t] = x@w + bias ----
        const char* xb = xbuf[c & 1];
        #pragma unroll
        for (int rt = 0; rt < 4; ++rt) {
            bf16x8 ax[4];
            #pragma unroll
            for (int ks = 0; ks < 4; ++ks) {
                int row = rt * 16 + l;   // row parity == l&1 (rt*16 even)
                const float* pr = reinterpret_cast<const float*>(
                    xb + (row >> 1) * XGRP + (row & 1) * 512 + (ks * 32 + q * 8) * 4);
                float4 u0 = *reinterpret_cast<const float4*>(pr);
                float4 u1 = *reinterpret_cast<const float4*>(pr + 4);
                bf16x8 f;
                f[0] = f2bf_rne(u0.x); f[1] = f2bf_rne(u0.y);
                f[2] = f2bf_rne(u0.z); f[3] = f2bf_rne(u0.w);
                f[4] = f2bf_rne(u1.x); f[5] = f2bf_rne(u1.y);
                f[6] = f2bf_rne(u1.z); f[7] = f2bf_rne(u1.w);
                ax[ks] = f;
            }
            #pragma unroll
            for (int nt = 0; nt < 8; ++nt) {
                f32x4 acc2;
                #pragma unroll
                for (int ks = 0; ks < 4; ++ks) {
                    bf16x8 bw = *reinterpret_cast<const bf16x8*>(
                        &wT[(nt * 16 + l) * WPAD + ks * 32 + q * 8]);
                    acc2 = __builtin_amdgcn_mfma_f32_16x16x32_bf16(
                        ax[ks], bw, ks == 0 ? zero4 : acc2, 0, 0, 0);
                }
                f32x4 o = (f32x4){acc2[0] + bv[nt], acc2[1] + bv[nt],
                                  acc2[2] + bv[nt], acc2[3] + bv[nt]};
                *reinterpret_cast<f32x4*>(&pT[(nt * 16 + l) * PPAD + rt * 16 + q * 4]) = o;
            }
        }

        // ---- issue DMA for chunk c+1 (zero VGPR footprint; drains at next barrier) ----
        if (c + 1 < NCH) {
            const char* gsrc = (const char*)(xrow + (size_t)(c + 1) * CH * H_N);
            char* ldst = &xbuf[(c + 1) & 1][0];
            #pragma unroll 1
            for (int k = 0; k < 32; ++k) {
                __builtin_amdgcn_global_load_lds(
                    (const __attribute__((address_space(1))) void*)(gsrc + k * 1024 + lane * 16),
                    (__attribute__((address_space(3))) void*)(ldst + k * XGRP),
                    16, 0, 0);
            }
        }

        int tstart = 0;
        if (c == 0) {
            // state0 = tanh(proj[0]) — no recurrent term
            float p0 = pT[(32 * q + l) * PPAD + 0];
            float p1 = pT[(32 * q + 16 + l) * PPAD + 0];
            y0 = tanh_fast(p0);
            y1 = tanh_fast(p1);
            sst[32 * q + l]      = f2bf_rne(y0);
            sst[32 * q + 16 + l] = f2bf_rne(y1);
            tstart = 1;
        }

        // ---- recurrence: 1 wave, no barriers, no per-step acc init, no spills ----
        #pragma unroll 1
        for (int t = tstart; t < CH; ++t) {
            bf16x8 a[4];
            #pragma unroll
            for (int ks = 0; ks < 4; ++ks)
                a[ks] = *reinterpret_cast<const bf16x8*>(&sst[ks * 32 + q * 8]);
            float p0 = pT[(32 * q + l) * PPAD + t];
            float p1 = pT[(32 * q + 16 + l) * PPAD + t];

            f32x4 acc[8];
            #pragma unroll
            for (int ks = 0; ks < 4; ++ks)       // ks-outer: first MFMA starts as soon as a[0] lands
                #pragma unroll
                for (int nt = 0; nt < 8; ++nt)
                    acc[nt] = __builtin_amdgcn_mfma_f32_16x16x32_bf16(
                        a[ks], wf[nt][ks], ks == 0 ? zero4 : acc[nt], 0, 0, 0);

            // lane (l,q) finalizes cols 32q+l and 32q+16+l (n-tiles 2q, 2q+1), D row 4q = reg 0
            float z0 = isq0 ? acc[0][0] : isq1 ? acc[2][0] : isq2 ? acc[4][0] : acc[6][0];
            float z1 = isq0 ? acc[1][0] : isq1 ? acc[3][0] : isq2 ? acc[5][0] : acc[7][0];
            y0 = tanh_fast(p0 + z0);
            y1 = tanh_fast(p1 + z1);
            sst[32 * q + l]      = f2bf_rne(y0);
            sst[32 * q + 16 + l] = f2bf_rne(y1);
        }
    }

    out[r * H_N + 32 * q + l]      = y0;
    out[r * H_N + 32 * q + 16 + l] = y1;
}

extern "C" void kernel_launch(void* const* d_in, const int* in_sizes, int n_in,
                              void* d_out, int out_size, void* d_ws, size_t ws_size,
                              hipStream_t stream) {
    const float* x    = (const float*)d_in[0];  // [B][T][D] fp32
    const float* w    = (const float*)d_in[1];  // [D][H]    fp32
    const float* wst  = (const float*)d_in[2];  // [H][H]    fp32
    const float* bias = (const float*)d_in[3];  // [H]       fp32
    float* out = (float*)d_out;                 // [B][H]    fp32

    k_fused<<<256, 64, 0, stream>>>(x, w, wst, bias, out);
}

// Round 6
// 464.408 us; speedup vs baseline: 1.4850x; 1.4241x over previous
//
#include <hip/hip_runtime.h>

#define T_N 1024
#define H_N 128
#define CH   64
#define NCH (T_N / CH)     // 16
#define WPAD 136           // shorts per row of bf16 weight tiles
#define PPAD 68            // floats per row of pT
#define XGRP 1040          // bytes per 2-row group in xbuf (1024 data + 16 pad)
#define XBUF_BYTES (32 * XGRP)

typedef __attribute__((ext_vector_type(8))) short bf16x8;
typedef __attribute__((ext_vector_type(4))) float f32x4;

__device__ __forceinline__ short f2bf_rne(float f) {
    union { float f; unsigned int i; } v; v.f = f;
    unsigned int r = v.i + 0x7FFFu + ((v.i >> 16) & 1u);
    return (short)(r >> 16);
}
__device__ __forceinline__ float tanh_fast(float x) {
    return 1.0f - 2.0f / (__expf(2.0f * x) + 1.0f);
}

// One block per batch row; 4 waves split the per-step matvec by column (nt pairs).
// All A-rows equal the state => D regs are row-replicated => no select chains.
__global__ __launch_bounds__(256, 1) void k_fused(const float* __restrict__ x,
                                                  const float* __restrict__ w,
                                                  const float* __restrict__ wst,
                                                  const float* __restrict__ bias,
                                                  float* __restrict__ out) {
    __shared__ __align__(16) short wT[H_N * WPAD];      // input-proj w, bf16 [n][k]
    __shared__ __align__(16) float pT[H_N * PPAD];      // proj chunk [h][t]; wsT staging at startup
    __shared__ __align__(16) char  xbuf[2][XBUF_BYTES]; // fp32 x chunk, DMA double buffer
    __shared__ __align__(16) short sst[2][H_N];         // state double buffer, bf16

    const int tid  = threadIdx.x;
    const int wv   = tid >> 6;       // wave: owns cols 32wv+l, 32wv+16+l (nt = 2wv, 2wv+1)
    const int lane = tid & 63;
    const int l = lane & 15;
    const int q = lane >> 4;
    const int r = blockIdx.x;
    const float* xrow = x + (size_t)r * T_N * H_N;
    const f32x4 zero4 = (f32x4){0.f, 0.f, 0.f, 0.f};

    // ---- DMA chunk 0 (wave wv loads groups 8wv..8wv+7) ----
    {
        const char* gsrc = (const char*)xrow;
        #pragma unroll
        for (int kk = 0; kk < 8; ++kk) {
            int k = wv * 8 + kk;
            __builtin_amdgcn_global_load_lds(
                (const __attribute__((address_space(1))) void*)(gsrc + k * 1024 + lane * 16),
                (__attribute__((address_space(3))) void*)(&xbuf[0][k * XGRP]),
                16, 0, 0);
        }
    }

    // ---- stage wst (bf16 [n][k]) through pT's memory ----
    short* wsT = reinterpret_cast<short*>(pT);
    for (int e = tid * 4; e < H_N * H_N; e += 1024) {
        int k = e >> 7, n = e & 127;
        float4 a4 = *reinterpret_cast<const float4*>(wst + e);
        wsT[(n + 0) * WPAD + k] = f2bf_rne(a4.x);
        wsT[(n + 1) * WPAD + k] = f2bf_rne(a4.y);
        wsT[(n + 2) * WPAD + k] = f2bf_rne(a4.z);
        wsT[(n + 3) * WPAD + k] = f2bf_rne(a4.w);
    }
    __syncthreads();   // wsT visible (also drains chunk-0 DMA early — once, cheap)

    // wave's own state-W B-frags: wf[b][ks] = wst[32ks+8q+j][16(2wv+b)+l]
    bf16x8 wf[2][4];
    #pragma unroll
    for (int b = 0; b < 2; ++b)
        #pragma unroll
        for (int ks = 0; ks < 4; ++ks)
            wf[b][ks] = *reinterpret_cast<const bf16x8*>(
                &wsT[(16 * (2 * wv + b) + l) * WPAD + ks * 32 + q * 8]);

    // ---- input-proj weights -> bf16 [n][k] LDS ----
    for (int e = tid * 4; e < H_N * H_N; e += 1024) {
        int k = e >> 7, n = e & 127;
        float4 a4 = *reinterpret_cast<const float4*>(w + e);
        wT[(n + 0) * WPAD + k] = f2bf_rne(a4.x);
        wT[(n + 1) * WPAD + k] = f2bf_rne(a4.y);
        wT[(n + 2) * WPAD + k] = f2bf_rne(a4.z);
        wT[(n + 3) * WPAD + k] = f2bf_rne(a4.w);
    }

    float bv[8];
    #pragma unroll
    for (int nt = 0; nt < 8; ++nt) bv[nt] = bias[nt * 16 + l];

    int par = 0;
    float y0 = 0.f, y1 = 0.f;

    #pragma unroll 1
    for (int c = 0; c < NCH; ++c) {
        // guarantees: wf reads done (c==0), prev chunk's steps done with pT,
        // xbuf[c&1] DMA drained, wT ready
        __syncthreads();

        // ---- chunk GEMM: wave wv computes proj rows [c*64+16wv .. +15] ----
        {
            const char* xb = xbuf[c & 1];
            int row = wv * 16 + l;
            const float* pr = reinterpret_cast<const float*>(
                xb + (row >> 1) * XGRP + (row & 1) * 512);
            bf16x8 ax[4];
            #pragma unroll
            for (int ks = 0; ks < 4; ++ks) {
                float4 u0 = *reinterpret_cast<const float4*>(pr + ks * 32 + q * 8);
                float4 u1 = *reinterpret_cast<const float4*>(pr + ks * 32 + q * 8 + 4);
                bf16x8 f;
                f[0] = f2bf_rne(u0.x); f[1] = f2bf_rne(u0.y);
                f[2] = f2bf_rne(u0.z); f[3] = f2bf_rne(u0.w);
                f[4] = f2bf_rne(u1.x); f[5] = f2bf_rne(u1.y);
                f[6] = f2bf_rne(u1.z); f[7] = f2bf_rne(u1.w);
                ax[ks] = f;
            }
            #pragma unroll
            for (int nt = 0; nt < 8; ++nt) {
                f32x4 acc;
                #pragma unroll
                for (int ks = 0; ks < 4; ++ks) {
                    bf16x8 bw = *reinterpret_cast<const bf16x8*>(
                        &wT[(nt * 16 + l) * WPAD + ks * 32 + q * 8]);
                    acc = __builtin_amdgcn_mfma_f32_16x16x32_bf16(
                        ax[ks], bw, ks == 0 ? zero4 : acc, 0, 0, 0);
                }
                f32x4 o = (f32x4){acc[0] + bv[nt], acc[1] + bv[nt],
                                  acc[2] + bv[nt], acc[3] + bv[nt]};
                *reinterpret_cast<f32x4*>(&pT[(nt * 16 + l) * PPAD + wv * 16 + q * 4]) = o;
            }
        }

        // ---- DMA chunk c+1 ----
        if (c + 1 < NCH) {
            const char* gsrc = (const char*)(xrow + (size_t)(c + 1) * CH * H_N);
            char* ldst = &xbuf[(c + 1) & 1][0];
            #pragma unroll
            for (int kk = 0; kk < 8; ++kk) {
                int k = wv * 8 + kk;
                __builtin_amdgcn_global_load_lds(
                    (const __attribute__((address_space(1))) void*)(gsrc + k * 1024 + lane * 16),
                    (__attribute__((address_space(3))) void*)(ldst + k * XGRP),
                    16, 0, 0);
            }
        }

        __syncthreads();   // pT ready

        int tstart = 0;
        if (c == 0) {
            if (tid < 128) sst[0][tid] = f2bf_rne(tanh_fast(pT[tid * PPAD + 0]));
            __syncthreads();
            tstart = 1;
            par = 0;
        }

        // p prefetch for first step of the chunk
        float p0 = pT[(32 * wv + l) * PPAD + tstart];
        float p1 = pT[(32 * wv + 16 + l) * PPAD + tstart];

        // ---- step loop: 1 barrier/step, depth-1 MFMA, no selects ----
        #pragma unroll 1
        for (int t = tstart; t < CH; ++t) {
            bf16x8 a[4];
            #pragma unroll
            for (int ks = 0; ks < 4; ++ks)
                a[ks] = *reinterpret_cast<const bf16x8*>(&sst[par][ks * 32 + q * 8]);

            // 8 independent MFMAs (b=0,1 x ks=0..3), each depth-1
            f32x4 acc[8];
            #pragma unroll
            for (int ks = 0; ks < 4; ++ks) {
                acc[ks]     = __builtin_amdgcn_mfma_f32_16x16x32_bf16(a[ks], wf[0][ks], zero4, 0, 0, 0);
                acc[4 + ks] = __builtin_amdgcn_mfma_f32_16x16x32_bf16(a[ks], wf[1][ks], zero4, 0, 0, 0);
            }

            // prefetch p for t+1 (state-independent, hides under MFMA tail)
            int tn = (t + 1 < CH) ? t + 1 : t;
            float np0 = pT[(32 * wv + l) * PPAD + tn];
            float np1 = pT[(32 * wv + 16 + l) * PPAD + tn];

            // rows replicated -> reg 0 of each acc is z for this wave's columns
            float z0 = p0 + ((acc[0][0] + acc[1][0]) + (acc[2][0] + acc[3][0]));
            float z1 = p1 + ((acc[4][0] + acc[5][0]) + (acc[6][0] + acc[7][0]));
            y0 = tanh_fast(z0);
            y1 = tanh_fast(z1);
            sst[par ^ 1][32 * wv + l]      = f2bf_rne(y0);
            sst[par ^ 1][32 * wv + 16 + l] = f2bf_rne(y1);
            p0 = np0; p1 = np1;
            par ^= 1;
            __syncthreads();   // y_t visible to all waves
        }
    }

    if (q == 0) {   // q-groups hold replicated results; one writer each
        out[r * H_N + 32 * wv + l]      = y0;
        out[r * H_N + 32 * wv + 16 + l] = y1;
    }
}

extern "C" void kernel_launch(void* const* d_in, const int* in_sizes, int n_in,
                              void* d_out, int out_size, void* d_ws, size_t ws_size,
                              hipStream_t stream) {
    const float* x    = (const float*)d_in[0];  // [B][T][D] fp32
    const float* w    = (const float*)d_in[1];  // [D][H]    fp32
    const float* wst  = (const float*)d_in[2];  // [H][H]    fp32
    const float* bias = (const float*)d_in[3];  // [H]       fp32
    float* out = (float*)d_out;                 // [B][H]    fp32

    k_fused<<<256, 256, 0, stream>>>(x, w, wst, bias, out);
}